// Round 4
// baseline (538.452 us; speedup 1.0000x reference)
//
#include <hip/hip_runtime.h>

// ---------------------------------------------------------------------------
// GAT encoder: x --GATConv(2 heads,128)--> ELU --> {GATConv mu, GATConv ls}
// N=50000, E=800000 (+self loops). fp32 in/out. Edges int32 w/ int64 detect.
// Round 11:
//  * k_agg: degree-sorted node pairing via counting sort (hist/scan/perm).
//    Paired nodes now have ~equal degree -> wave divergence max(d0,d1)~d,
//    blocks uniform -> occupancy tail shrinks. Inner loop unchanged (R10).
//  * GEMM: register prefetch of next stage chunk + A frag; raw s_barrier with
//    lgkmcnt(0)-only waits (no vmcnt drain) so prefetches stay in flight
//    across barriers (T3-minimum). k_cvt fused into gemm1 (AF32 path).
//  * R10 post-mortem: VALUBusy 52->41 as predicted but time 68.6->64 only;
//    k_agg is gather-latency/issue-floor bound, not VALU-chain bound.
// ---------------------------------------------------------------------------

typedef unsigned short u16;
typedef unsigned int u32;
typedef _Float16 f16;
typedef f16 f16x8 __attribute__((ext_vector_type(8)));
typedef float f32x4v __attribute__((ext_vector_type(4)));

__device__ __forceinline__ u16 f2h(float f) {
    union { f16 h; u16 u; } t;
    t.h = (f16)f;
    return t.u;
}
__device__ __forceinline__ float4 loadh4(const u16* __restrict__ p, size_t i) {
    union { uint2 u; f16 h[4]; } t;
    t.u = *(const uint2*)(p + i);
    return make_float4((float)t.h[0], (float)t.h[1], (float)t.h[2], (float)t.h[3]);
}
__device__ __forceinline__ void store4(float* __restrict__ p, size_t i, float4 v) {
    *(float4*)(p + i) = v;
}
__device__ __forceinline__ void store4(u16* __restrict__ p, size_t i, float4 v) {
    union { uint2 u; f16 h[4]; } t;
    t.h[0] = (f16)v.x; t.h[1] = (f16)v.y; t.h[2] = (f16)v.z; t.h[3] = (f16)v.w;
    *(uint2*)(p + i) = t.u;
}

// ---------------- edge dtype detect + normalize (+degree count) --------------
__global__ __launch_bounds__(256) void k_detect(const u32* __restrict__ ebuf,
                                                int* __restrict__ flag) {
    __shared__ int nz;
    if (threadIdx.x == 0) nz = 0;
    __syncthreads();
    if (ebuf[2 * threadIdx.x + 1] != 0u) atomicAdd(&nz, 1);
    __syncthreads();
    if (threadIdx.x == 0) *flag = (nz == 0) ? 1 : 0;
}

__global__ __launch_bounds__(256) void k_extract(const u32* __restrict__ ebuf, int E,
                                                 const int* __restrict__ flag,
                                                 int* __restrict__ se,
                                                 int* __restrict__ de,
                                                 int* __restrict__ deg) {
    int e = blockIdx.x * 256 + threadIdx.x;
    if (e >= E) return;
    int s, d;
    if (*flag) {  // int64 layout
        s = (int)ebuf[2 * (size_t)e];
        d = (int)ebuf[2 * ((size_t)E + (size_t)e)];
    } else {  // int32 layout
        s = (int)ebuf[e];
        d = (int)ebuf[(size_t)E + (size_t)e];
    }
    se[e] = s;
    de[e] = d;
    atomicAdd(&deg[d], 1);
}

// ---------------- degree counting sort (64 bins) -----------------------------
__global__ __launch_bounds__(256) void k_hist(const int* __restrict__ deg, int n,
                                              int* __restrict__ hist) {
    __shared__ int hs[64];
    if (threadIdx.x < 64) hs[threadIdx.x] = 0;
    __syncthreads();
    int i = blockIdx.x * 256 + threadIdx.x;
    if (i < n) atomicAdd(&hs[min(deg[i], 63)], 1);
    __syncthreads();
    if (threadIdx.x < 64 && hs[threadIdx.x]) atomicAdd(&hist[threadIdx.x], hs[threadIdx.x]);
}

__global__ void k_hscan(const int* __restrict__ hist, int* __restrict__ hcur) {
    int t = threadIdx.x;  // 64 threads
    int h0 = hist[t];
    int v = h0;
    for (int off = 1; off < 64; off <<= 1) {
        int u = __shfl_up(v, off, 64);
        if (t >= off) v += u;
    }
    hcur[t] = v - h0;  // exclusive
}

__global__ __launch_bounds__(256) void k_perm(const int* __restrict__ deg, int n,
                                              int* __restrict__ hcur,
                                              int* __restrict__ perm) {
    int i = blockIdx.x * 256 + threadIdx.x;
    if (i < n) {
        int pos = atomicAdd(&hcur[min(deg[i], 63)], 1);
        perm[pos] = i;
    }
}

// ---------------- CSR build ----------------
__global__ __launch_bounds__(256) void k_scan_a(const int* __restrict__ deg, int n,
                                                int* __restrict__ bsum) {
    __shared__ int s[256];
    int i = blockIdx.x * 256 + threadIdx.x;
    s[threadIdx.x] = (i < n) ? deg[i] : 0;
    __syncthreads();
    for (int st = 128; st > 0; st >>= 1) {
        if (threadIdx.x < st) s[threadIdx.x] += s[threadIdx.x + st];
        __syncthreads();
    }
    if (threadIdx.x == 0) bsum[blockIdx.x] = s[0];
}

__global__ __launch_bounds__(256) void k_scan_b(int* __restrict__ bsum, int nb) {
    __shared__ int s[256];
    int t = threadIdx.x;
    int v = (t < nb) ? bsum[t] : 0;
    s[t] = v;
    __syncthreads();
    for (int off = 1; off < 256; off <<= 1) {
        int add = (t >= off) ? s[t - off] : 0;
        __syncthreads();
        s[t] += add;
        __syncthreads();
    }
    if (t < nb) bsum[t] = s[t] - v;  // exclusive
}

__global__ __launch_bounds__(256) void k_scan_c(const int* __restrict__ deg, int n,
                                                const int* __restrict__ bsum,
                                                int* __restrict__ rowptr,
                                                int* __restrict__ cursor, int E) {
    __shared__ int s[256];
    int t = threadIdx.x;
    int i = blockIdx.x * 256 + t;
    int v = (i < n) ? deg[i] : 0;
    s[t] = v;
    __syncthreads();
    for (int off = 1; off < 256; off <<= 1) {
        int add = (t >= off) ? s[t - off] : 0;
        __syncthreads();
        s[t] += add;
        __syncthreads();
    }
    if (i < n) {
        int ex = bsum[blockIdx.x] + s[t] - v;
        rowptr[i] = ex;
        cursor[i] = ex;
    }
    if (i == 0) rowptr[n] = E;
}

__global__ __launch_bounds__(256) void k_fill(const int* __restrict__ src,
                                              const int* __restrict__ dst, int E,
                                              int* __restrict__ cursor,
                                              int* __restrict__ csr_src,
                                              int* __restrict__ csr_dst) {
    int e = blockIdx.x * 256 + threadIdx.x;
    if (e < E) {
        int d = dst[e];
        int slot = atomicAdd(&cursor[d], 1);
        csr_src[slot] = src[e];
        csr_dst[slot] = d;
    }
}

// Wt[c][k] = W[k][c] as fp16.  split==256: single W (row stride 256);
// split==128: c<128 from Wl, else Wr (row stride 128).
__global__ __launch_bounds__(256) void k_tw(const float* __restrict__ Wl,
                                            const float* __restrict__ Wr, int split,
                                            int K, u16* __restrict__ Wt) {
    int idx = blockIdx.x * 256 + threadIdx.x;
    if (idx >= 256 * K) return;
    int c = idx / K, k = idx - c * K;
    float v;
    if (split == 256)
        v = Wl[(size_t)k * 256 + c];
    else
        v = (c < 128) ? Wl[(size_t)k * 128 + c] : Wr[(size_t)k * 128 + (c - 128)];
    Wt[idx] = f2h(v);
}

// ---------------- edge-weight precompute (CSR order, per-slot planes) --------
template <int NS>
__global__ __launch_bounds__(256) void k_w(const int* __restrict__ csr_src,
                                           const int* __restrict__ csr_dst,
                                           const float* __restrict__ as,
                                           const float* __restrict__ ad,
                                           float* __restrict__ wp, int E) {
    int i = blockIdx.x * 256 + threadIdx.x;
    if (i >= E) return;
    int s = csr_src[i], d = csr_dst[i];
    if (NS == 2) {
        float2 a = *(const float2*)(as + (size_t)s * 2);
        float2 b = *(const float2*)(ad + (size_t)d * 2);
        float e0 = a.x + b.x, e1 = a.y + b.y;
        e0 = fmaxf(e0, 0.2f * e0);
        e1 = fmaxf(e1, 0.2f * e1);
        wp[i] = __expf(e0);
        wp[(size_t)E + i] = __expf(e1);
    } else {
        float4 a = *(const float4*)(as + (size_t)s * 4);
        float4 b = *(const float4*)(ad + (size_t)d * 4);
        float e0 = a.x + b.x, e1 = a.y + b.y, e2 = a.z + b.z, e3 = a.w + b.w;
        e0 = fmaxf(e0, 0.2f * e0);
        e1 = fmaxf(e1, 0.2f * e1);
        e2 = fmaxf(e2, 0.2f * e2);
        e3 = fmaxf(e3, 0.2f * e3);
        wp[i] = __expf(e0);
        wp[(size_t)E + i] = __expf(e1);
        wp[2 * (size_t)E + i] = __expf(e2);
        wp[3 * (size_t)E + i] = __expf(e3);
    }
}

// ---------------- MFMA GEMM + fused alpha epilogue --------------------------
// h[M,256](f16) = A[M,K] @ W[K,256]; Wt = W^T fp16 [256][K]. AF32: A is fp32
// (layer 1 reads x directly; cvt fused). Software pipeline: next chunk's
// stage regs + A frag prefetched during MFMA; barriers are raw s_barrier with
// lgkmcnt(0)-only waits so global prefetches stay in flight (no vmcnt drain).
template <int K, int ALOGW, bool AF32>
__global__ __launch_bounds__(256) void k_gemm_mfma(
    const void* __restrict__ Av, const u16* __restrict__ Wt, u16* __restrict__ out,
    float* __restrict__ as_out, float* __restrict__ ad_out,
    const float* __restrict__ alo, const float* __restrict__ ahi,
    const float* __restrict__ dlo, const float* __restrict__ dhi, int M) {
    __shared__ u16 Bs[256 * 40];  // 20KB
    const int tid = threadIdx.x;
    const int wave = tid >> 6;
    const int lane = tid & 63;
    const int li = lane & 15;
    const int quad = lane >> 4;
    const int r0 = blockIdx.x * 64 + wave * 16;
    int arowi = r0 + li;
    if (arowi >= M) arowi = M - 1;  // clamp (stores are guarded)
    const u16* arow16 = (const u16*)Av + (AF32 ? 0 : (size_t)arowi * K + quad * 8);
    const float* arow32 = (const float*)Av + (AF32 ? (size_t)arowi * K + quad * 8 : 0);

    f32x4v acc[16];
#pragma unroll
    for (int ct = 0; ct < 16; ct++) acc[ct] = (f32x4v)(0.f);

    const u16* wrow = Wt + (size_t)tid * K;
    u16* dstp = Bs + tid * 40;
    // prologue prefetch (chunk 0)
    uint4 sv0 = ((const uint4*)wrow)[0];
    uint4 sv1 = ((const uint4*)(wrow + 8))[0];
    uint4 sv2 = ((const uint4*)(wrow + 16))[0];
    uint4 sv3 = ((const uint4*)(wrow + 24))[0];
    uint4 apf0, apf1;
    if (AF32) {
        apf0 = *(const uint4*)(arow32);
        apf1 = *(const uint4*)(arow32 + 4);
    } else {
        apf0 = *(const uint4*)(arow16);
        apf1 = apf0;
    }

    for (int t = 0; t < K; t += 32) {
        asm volatile("s_waitcnt lgkmcnt(0)" ::: "memory");
        __builtin_amdgcn_s_barrier();  // Bs free for writing (prior reads done)
        ((uint4*)dstp)[0] = sv0;
        ((uint4*)(dstp + 8))[0] = sv1;
        ((uint4*)(dstp + 16))[0] = sv2;
        ((uint4*)(dstp + 24))[0] = sv3;
        f16x8 a;
        if (AF32) {
            union { uint4 u; float f[4]; } ua, ub;
            ua.u = apf0;
            ub.u = apf1;
            a[0] = (f16)ua.f[0]; a[1] = (f16)ua.f[1];
            a[2] = (f16)ua.f[2]; a[3] = (f16)ua.f[3];
            a[4] = (f16)ub.f[0]; a[5] = (f16)ub.f[1];
            a[6] = (f16)ub.f[2]; a[7] = (f16)ub.f[3];
        } else {
            union { uint4 u; f16x8 h; } uh;
            uh.u = apf0;
            a = uh.h;
        }
        if (t + 32 < K) {  // prefetch next chunk; stays in flight across barrier
            const u16* s2 = wrow + t + 32;
            sv0 = ((const uint4*)s2)[0];
            sv1 = ((const uint4*)(s2 + 8))[0];
            sv2 = ((const uint4*)(s2 + 16))[0];
            sv3 = ((const uint4*)(s2 + 24))[0];
            if (AF32) {
                apf0 = *(const uint4*)(arow32 + t + 32);
                apf1 = *(const uint4*)(arow32 + t + 36);
            } else {
                apf0 = *(const uint4*)(arow16 + t + 32);
            }
        }
        asm volatile("s_waitcnt lgkmcnt(0)" ::: "memory");
        __builtin_amdgcn_s_barrier();  // Bs ready (all ds_writes drained)
#pragma unroll
        for (int ct = 0; ct < 16; ct++) {
            f16x8 b = *(const f16x8*)(Bs + (ct * 16 + li) * 40 + quad * 8);
            acc[ct] = __builtin_amdgcn_mfma_f32_16x16x32_f16(a, b, acc[ct], 0, 0, 0);
        }
    }

    // h store (fp16): D row = quad*4+reg, col = ct*16+li
#pragma unroll
    for (int reg = 0; reg < 4; reg++) {
        int grow = r0 + quad * 4 + reg;
        if (grow < M) {
            u16* orow = out + (size_t)grow * 256 + li;
#pragma unroll
            for (int ct = 0; ct < 16; ct++) orow[ct * 16] = f2h(acc[ct][reg]);
        }
    }

    // fused alpha epilogue
    const int NS = 64 >> ALOGW;   // 2 or 4
    const int SH = ALOGW - 2;     // slot = ct >> SH
    float aw[16], dw[16];
#pragma unroll
    for (int ct = 0; ct < 16; ct++) {
        int col = ct * 16 + li;
        aw[ct] = (col < 128) ? alo[col] : ahi[col - 128];
        dw[ct] = (col < 128) ? dlo[col] : dhi[col - 128];
    }
#pragma unroll
    for (int reg = 0; reg < 4; reg++) {
        float s[4] = {0.f, 0.f, 0.f, 0.f};
        float d[4] = {0.f, 0.f, 0.f, 0.f};
#pragma unroll
        for (int ct = 0; ct < 16; ct++) {
            int sl = ct >> SH;
            s[sl] += acc[ct][reg] * aw[ct];
            d[sl] += acc[ct][reg] * dw[ct];
        }
#pragma unroll
        for (int sl = 0; sl < NS; sl++) {
#pragma unroll
            for (int m = 1; m <= 8; m <<= 1) {
                s[sl] += __shfl_xor(s[sl], m, 64);
                d[sl] += __shfl_xor(d[sl], m, 64);
            }
        }
        int grow = r0 + quad * 4 + reg;
        if (li == 0 && grow < M) {
#pragma unroll
            for (int sl = 0; sl < NS; sl++) {
                as_out[(size_t)grow * NS + sl] = s[sl];
                ad_out[(size_t)grow * NS + sl] = d[sl];
            }
        }
    }
}

// ---------------- aggregation (softmax-weighted gather) ----------------------
// Column-half split with XCD-group affinity; 32-lane half-wave owns one dst
// node (from degree-sorted perm -> paired nodes have ~equal degree, blocks
// uniform). Lane owns 4 channels (8B gathers); weights from wp planes; 8-wide
// unroll keeps 8x512B in flight per wave.
// MODE 0: +bias, ELU, write fp16 x1 [n,256]. MODE 1: +bias, write fp32 mu/ls.
template <int LOGW, int MODE, typename OT>
__global__ __launch_bounds__(256) void k_agg4(
    const u16* __restrict__ h, const int* __restrict__ rowptr,
    const int* __restrict__ csr_src, const float* __restrict__ wp,
    const float* __restrict__ as, const float* __restrict__ ad,
    const float* __restrict__ b_lo, const float* __restrict__ b_hi,
    const int* __restrict__ perm, OT* __restrict__ outp, int n, int nGrp, int E) {
    const int NS = 64 >> LOGW;  // total alpha slots (2 or 4)
    const int bid = blockIdx.x;
    const int xcd = bid & 7;
    const int half = xcd >> 2;                  // 0: cols 0-127, 1: cols 128-255
    const int grp = (bid >> 3) * 4 + (xcd & 3); // node group within half
    if (grp >= nGrp) return;
    const int lane = threadIdx.x & 63;
    const int sub = lane >> 5;   // which node of the wave's pair
    const int sl = lane & 31;    // lane within the node
    const int idx = grp * 8 + (threadIdx.x >> 6) * 2 + sub;
    const bool ok = idx < n;
    const int wid = perm[ok ? idx : 0];  // degree-sorted node id
    const int col = half * 128 + sl * 4;
    const int slot = col >> (LOGW + 2);
    const float* __restrict__ wpl = wp + (size_t)slot * E;

    // self-loop weight
    float e = as[(size_t)wid * NS + slot] + ad[(size_t)wid * NS + slot];
    e = fmaxf(e, 0.2f * e);  // LeakyReLU(0.2)
    float w = __expf(e);
    float denom = w;
    float4 hv = loadh4(h, (size_t)wid * 256 + col);
    float acc0 = w * hv.x, acc1 = w * hv.y, acc2 = w * hv.z, acc3 = w * hv.w;

    int rb = 0, re = 0;
    if (ok) { rb = rowptr[wid]; re = rowptr[wid + 1]; }
    int p = rb;
    for (; p + 8 <= re; p += 8) {
        int4 sA = *(const int4*)(csr_src + p);
        int4 sB = *(const int4*)(csr_src + p + 4);
        float4 wA = *(const float4*)(wpl + p);
        float4 wB = *(const float4*)(wpl + p + 4);
        float4 h0 = loadh4(h, (size_t)sA.x * 256 + col);
        float4 h1 = loadh4(h, (size_t)sA.y * 256 + col);
        float4 h2 = loadh4(h, (size_t)sA.z * 256 + col);
        float4 h3 = loadh4(h, (size_t)sA.w * 256 + col);
        float4 h4 = loadh4(h, (size_t)sB.x * 256 + col);
        float4 h5 = loadh4(h, (size_t)sB.y * 256 + col);
        float4 h6 = loadh4(h, (size_t)sB.z * 256 + col);
        float4 h7 = loadh4(h, (size_t)sB.w * 256 + col);
        denom += (wA.x + wA.y + wA.z + wA.w) + (wB.x + wB.y + wB.z + wB.w);
        acc0 += wA.x * h0.x + wA.y * h1.x + wA.z * h2.x + wA.w * h3.x +
                wB.x * h4.x + wB.y * h5.x + wB.z * h6.x + wB.w * h7.x;
        acc1 += wA.x * h0.y + wA.y * h1.y + wA.z * h2.y + wA.w * h3.y +
                wB.x * h4.y + wB.y * h5.y + wB.z * h6.y + wB.w * h7.y;
        acc2 += wA.x * h0.z + wA.y * h1.z + wA.z * h2.z + wA.w * h3.z +
                wB.x * h4.z + wB.y * h5.z + wB.z * h6.z + wB.w * h7.z;
        acc3 += wA.x * h0.w + wA.y * h1.w + wA.z * h2.w + wA.w * h3.w +
                wB.x * h4.w + wB.y * h5.w + wB.z * h6.w + wB.w * h7.w;
    }
    for (; p + 4 <= re; p += 4) {
        int4 sA = *(const int4*)(csr_src + p);
        float4 wA = *(const float4*)(wpl + p);
        float4 h0 = loadh4(h, (size_t)sA.x * 256 + col);
        float4 h1 = loadh4(h, (size_t)sA.y * 256 + col);
        float4 h2 = loadh4(h, (size_t)sA.z * 256 + col);
        float4 h3 = loadh4(h, (size_t)sA.w * 256 + col);
        denom += (wA.x + wA.y) + (wA.z + wA.w);
        acc0 += wA.x * h0.x + wA.y * h1.x + wA.z * h2.x + wA.w * h3.x;
        acc1 += wA.x * h0.y + wA.y * h1.y + wA.z * h2.y + wA.w * h3.y;
        acc2 += wA.x * h0.z + wA.y * h1.z + wA.z * h2.z + wA.w * h3.z;
        acc3 += wA.x * h0.w + wA.y * h1.w + wA.z * h2.w + wA.w * h3.w;
    }
    for (; p < re; ++p) {
        int s = csr_src[p];
        float ww = wpl[p];
        float4 hh = loadh4(h, (size_t)s * 256 + col);
        denom += ww;
        acc0 += ww * hh.x;
        acc1 += ww * hh.y;
        acc2 += ww * hh.z;
        acc3 += ww * hh.w;
    }
    float inv = 1.0f / (denom + 1e-16f);

    const float* bp = half ? b_hi : b_lo;
    const int ci = sl * 4;
    float4 bv = *(const float4*)(bp + ci);
    float v0 = acc0 * inv + bv.x;
    float v1 = acc1 * inv + bv.y;
    float v2 = acc2 * inv + bv.z;
    float v3 = acc3 * inv + bv.w;

    if (!ok) return;
    if (MODE == 0) {  // ELU -> x1 fp16 [n,256]
        v0 = v0 > 0.f ? v0 : expm1f(v0);
        v1 = v1 > 0.f ? v1 : expm1f(v1);
        v2 = v2 > 0.f ? v2 : expm1f(v2);
        v3 = v3 > 0.f ? v3 : expm1f(v3);
        store4((u16*)outp, (size_t)wid * 256 + col, make_float4(v0, v1, v2, v3));
    } else {  // half 0 -> mu [n,128]; half 1 -> logstd [n,128] (concatenated)
        size_t base = half ? ((size_t)n * 128 + (size_t)wid * 128 + ci)
                           : ((size_t)wid * 128 + ci);
        store4((float*)outp, base, make_float4(v0, v1, v2, v3));
    }
}

// ---------------------------------------------------------------------------
extern "C" void kernel_launch(void* const* d_in, const int* in_sizes, int n_in,
                              void* d_out, int out_size, void* d_ws, size_t ws_size,
                              hipStream_t stream) {
    const float* x = (const float*)d_in[0];
    const u32* ebuf = (const u32*)d_in[1];
    const float* W1 = (const float*)d_in[2];
    const float* a_src1 = (const float*)d_in[3];
    const float* a_dst1 = (const float*)d_in[4];
    const float* b1 = (const float*)d_in[5];
    const float* W_mu = (const float*)d_in[6];
    const float* a_src_mu = (const float*)d_in[7];
    const float* a_dst_mu = (const float*)d_in[8];
    const float* b_mu = (const float*)d_in[9];
    const float* W_ls = (const float*)d_in[10];
    const float* a_src_ls = (const float*)d_in[11];
    const float* a_dst_ls = (const float*)d_in[12];
    const float* b_ls = (const float*)d_in[13];

    const int n = in_sizes[0] / 128;  // 50000
    const int E = in_sizes[1] / 2;    // 800000

    char* base = (char*)d_ws;
    size_t off = 0;
    auto alloc = [&](size_t b) -> char* {
        char* p = base + off;
        off = (off + b + 255) & ~(size_t)255;
        return p;
    };
    int* rowptr = (int*)alloc((size_t)(n + 1) * 4);
    int* cursor = (int*)alloc((size_t)n * 4);
    int* csr = (int*)alloc((size_t)E * 4);
    int* csrd = (int*)alloc((size_t)E * 4);
    int* bsum = (int*)alloc(256 * 4);
    int* eflag = (int*)alloc(256);
    int* se = (int*)alloc((size_t)E * 4);
    int* de = (int*)alloc((size_t)E * 4);
    int* perm = (int*)alloc((size_t)n * 4);
    int* hist = (int*)alloc(64 * 4);
    int* hcur = (int*)alloc(64 * 4);
    float* as = (float*)alloc((size_t)n * 4 * 4);
    float* ad = (float*)alloc((size_t)n * 4 * 4);
    float* wp = (float*)alloc((size_t)E * 4 * 4);  // edge-weight planes (<=4)
    u16* W1t = (u16*)alloc(256 * 128 * 2);        // W1^T fp16 [256][128]
    u16* Wt2 = (u16*)alloc(256 * 256 * 2);        // [W_mu|W_ls]^T fp16 [256][256]
    u16* x1h = (u16*)alloc((size_t)n * 256 * 2);  // x1 fp16 [n,256]
    u16* h = (u16*)alloc((size_t)n * 256 * 2);    // h fp16 (both layers)

    const int nb = (n + 255) / 256;
    const int eg = (E + 255) / 256;
    const int gg = (n + 63) / 64;
    const int nGrp = (n + 7) / 8;                 // 8 dst nodes per block/half
    const int aggGrid = 8 * ((nGrp + 3) / 4);     // 2 halves x 4-XCD groups

    // edge normalize + CSR build + degree sort (reused by all three convs)
    hipMemsetAsync(cursor, 0, (size_t)n * 4, stream);
    hipMemsetAsync(hist, 0, 64 * 4, stream);
    k_detect<<<1, 256, 0, stream>>>(ebuf, eflag);
    k_extract<<<eg, 256, 0, stream>>>(ebuf, E, eflag, se, de, cursor);
    k_hist<<<nb, 256, 0, stream>>>(cursor, n, hist);
    k_hscan<<<1, 64, 0, stream>>>(hist, hcur);
    k_perm<<<nb, 256, 0, stream>>>(cursor, n, hcur, perm);
    k_scan_a<<<nb, 256, 0, stream>>>(cursor, n, bsum);
    k_scan_b<<<1, 256, 0, stream>>>(bsum, nb);
    k_scan_c<<<nb, 256, 0, stream>>>(cursor, n, bsum, rowptr, cursor, E);
    k_fill<<<eg, 256, 0, stream>>>(se, de, E, cursor, csr, csrd);

    // weight transposes (fp16)
    k_tw<<<(256 * 128 + 255) / 256, 256, 0, stream>>>(W1, W1, 256, 128, W1t);
    k_tw<<<(256 * 256 + 255) / 256, 256, 0, stream>>>(W_mu, W_ls, 128, 256, Wt2);

    // Layer 1: h = x@W1 (MFMA, fp32 A, fused alphas); w planes; aggregate
    k_gemm_mfma<128, 5, true><<<gg, 256, 0, stream>>>(x, W1t, h, as, ad, a_src1,
                                                      a_src1 + 128, a_dst1,
                                                      a_dst1 + 128, n);
    k_w<2><<<eg, 256, 0, stream>>>(csr, csrd, as, ad, wp, E);
    k_agg4<5, 0, u16><<<aggGrid, 256, 0, stream>>>(h, rowptr, csr, wp, as, ad, b1,
                                                   b1 + 128, perm, x1h, n, nGrp, E);

    // Layers mu & ls: h = x1@[W_mu|W_ls] (MFMA, fused alphas); w; aggregate
    k_gemm_mfma<256, 4, false><<<gg, 256, 0, stream>>>(x1h, Wt2, h, as, ad,
                                                       a_src_mu, a_src_ls,
                                                       a_dst_mu, a_dst_ls, n);
    k_w<4><<<eg, 256, 0, stream>>>(csr, csrd, as, ad, wp, E);
    k_agg4<4, 1, float><<<aggGrid, 256, 0, stream>>>(h, rowptr, csr, wp, as, ad,
                                                     b_mu, b_ls, perm,
                                                     (float*)d_out, n, nGrp, E);
}

// Round 5
// 388.425 us; speedup vs baseline: 1.3862x; 1.3862x over previous
//
#include <hip/hip_runtime.h>

// ---------------------------------------------------------------------------
// GAT encoder: x --GATConv(2 heads,128)--> ELU --> {GATConv mu, GATConv ls}
// N=50000, E=800000 (+self loops). fp32 in/out. Edges int32 w/ int64 detect.
// Round 12:
//  * REVERT degree sort (R11): k_perm was 133us of same-address global
//    atomics (50000 adds onto 64 addresses). k_agg4 back to R10 direct-id
//    form (known 63-65us).
//  * GEMM M_rep=2: wave owns 32 rows (two A frags, acc[2][16]); each B
//    ds_read_b128 now feeds 2 MFMAs. Old ratio per chunk: 16 ds_read
//    (~192cyc) vs 16 MFMA (~88cyc) = LDS-read bound; new: 192 vs 176,
//    balanced. Grid halves (128 rows/block). VGPR ~190 -> 2 waves/SIMD.
//  * Keep R11 GEMM pipeline (reg prefetch + raw s_barrier, lgkm-only waits)
//    and cvt-fused fp32 A path (both measured ~neutral, structurally good).
// ---------------------------------------------------------------------------

typedef unsigned short u16;
typedef unsigned int u32;
typedef _Float16 f16;
typedef f16 f16x8 __attribute__((ext_vector_type(8)));
typedef float f32x4v __attribute__((ext_vector_type(4)));

__device__ __forceinline__ u16 f2h(float f) {
    union { f16 h; u16 u; } t;
    t.h = (f16)f;
    return t.u;
}
__device__ __forceinline__ float4 loadh4(const u16* __restrict__ p, size_t i) {
    union { uint2 u; f16 h[4]; } t;
    t.u = *(const uint2*)(p + i);
    return make_float4((float)t.h[0], (float)t.h[1], (float)t.h[2], (float)t.h[3]);
}
__device__ __forceinline__ void store4(float* __restrict__ p, size_t i, float4 v) {
    *(float4*)(p + i) = v;
}
__device__ __forceinline__ void store4(u16* __restrict__ p, size_t i, float4 v) {
    union { uint2 u; f16 h[4]; } t;
    t.h[0] = (f16)v.x; t.h[1] = (f16)v.y; t.h[2] = (f16)v.z; t.h[3] = (f16)v.w;
    *(uint2*)(p + i) = t.u;
}

// ---------------- edge dtype detect + normalize (+degree count) --------------
__global__ __launch_bounds__(256) void k_detect(const u32* __restrict__ ebuf,
                                                int* __restrict__ flag) {
    __shared__ int nz;
    if (threadIdx.x == 0) nz = 0;
    __syncthreads();
    if (ebuf[2 * threadIdx.x + 1] != 0u) atomicAdd(&nz, 1);
    __syncthreads();
    if (threadIdx.x == 0) *flag = (nz == 0) ? 1 : 0;
}

__global__ __launch_bounds__(256) void k_extract(const u32* __restrict__ ebuf, int E,
                                                 const int* __restrict__ flag,
                                                 int* __restrict__ se,
                                                 int* __restrict__ de,
                                                 int* __restrict__ deg) {
    int e = blockIdx.x * 256 + threadIdx.x;
    if (e >= E) return;
    int s, d;
    if (*flag) {  // int64 layout
        s = (int)ebuf[2 * (size_t)e];
        d = (int)ebuf[2 * ((size_t)E + (size_t)e)];
    } else {  // int32 layout
        s = (int)ebuf[e];
        d = (int)ebuf[(size_t)E + (size_t)e];
    }
    se[e] = s;
    de[e] = d;
    atomicAdd(&deg[d], 1);
}

// ---------------- CSR build ----------------
__global__ __launch_bounds__(256) void k_scan_a(const int* __restrict__ deg, int n,
                                                int* __restrict__ bsum) {
    __shared__ int s[256];
    int i = blockIdx.x * 256 + threadIdx.x;
    s[threadIdx.x] = (i < n) ? deg[i] : 0;
    __syncthreads();
    for (int st = 128; st > 0; st >>= 1) {
        if (threadIdx.x < st) s[threadIdx.x] += s[threadIdx.x + st];
        __syncthreads();
    }
    if (threadIdx.x == 0) bsum[blockIdx.x] = s[0];
}

__global__ __launch_bounds__(256) void k_scan_b(int* __restrict__ bsum, int nb) {
    __shared__ int s[256];
    int t = threadIdx.x;
    int v = (t < nb) ? bsum[t] : 0;
    s[t] = v;
    __syncthreads();
    for (int off = 1; off < 256; off <<= 1) {
        int add = (t >= off) ? s[t - off] : 0;
        __syncthreads();
        s[t] += add;
        __syncthreads();
    }
    if (t < nb) bsum[t] = s[t] - v;  // exclusive
}

__global__ __launch_bounds__(256) void k_scan_c(const int* __restrict__ deg, int n,
                                                const int* __restrict__ bsum,
                                                int* __restrict__ rowptr,
                                                int* __restrict__ cursor, int E) {
    __shared__ int s[256];
    int t = threadIdx.x;
    int i = blockIdx.x * 256 + t;
    int v = (i < n) ? deg[i] : 0;
    s[t] = v;
    __syncthreads();
    for (int off = 1; off < 256; off <<= 1) {
        int add = (t >= off) ? s[t - off] : 0;
        __syncthreads();
        s[t] += add;
        __syncthreads();
    }
    if (i < n) {
        int ex = bsum[blockIdx.x] + s[t] - v;
        rowptr[i] = ex;
        cursor[i] = ex;
    }
    if (i == 0) rowptr[n] = E;
}

__global__ __launch_bounds__(256) void k_fill(const int* __restrict__ src,
                                              const int* __restrict__ dst, int E,
                                              int* __restrict__ cursor,
                                              int* __restrict__ csr_src,
                                              int* __restrict__ csr_dst) {
    int e = blockIdx.x * 256 + threadIdx.x;
    if (e < E) {
        int d = dst[e];
        int slot = atomicAdd(&cursor[d], 1);
        csr_src[slot] = src[e];
        csr_dst[slot] = d;
    }
}

// Wt[c][k] = W[k][c] as fp16.  split==256: single W (row stride 256);
// split==128: c<128 from Wl, else Wr (row stride 128).
__global__ __launch_bounds__(256) void k_tw(const float* __restrict__ Wl,
                                            const float* __restrict__ Wr, int split,
                                            int K, u16* __restrict__ Wt) {
    int idx = blockIdx.x * 256 + threadIdx.x;
    if (idx >= 256 * K) return;
    int c = idx / K, k = idx - c * K;
    float v;
    if (split == 256)
        v = Wl[(size_t)k * 256 + c];
    else
        v = (c < 128) ? Wl[(size_t)k * 128 + c] : Wr[(size_t)k * 128 + (c - 128)];
    Wt[idx] = f2h(v);
}

// ---------------- edge-weight precompute (CSR order, per-slot planes) --------
template <int NS>
__global__ __launch_bounds__(256) void k_w(const int* __restrict__ csr_src,
                                           const int* __restrict__ csr_dst,
                                           const float* __restrict__ as,
                                           const float* __restrict__ ad,
                                           float* __restrict__ wp, int E) {
    int i = blockIdx.x * 256 + threadIdx.x;
    if (i >= E) return;
    int s = csr_src[i], d = csr_dst[i];
    if (NS == 2) {
        float2 a = *(const float2*)(as + (size_t)s * 2);
        float2 b = *(const float2*)(ad + (size_t)d * 2);
        float e0 = a.x + b.x, e1 = a.y + b.y;
        e0 = fmaxf(e0, 0.2f * e0);
        e1 = fmaxf(e1, 0.2f * e1);
        wp[i] = __expf(e0);
        wp[(size_t)E + i] = __expf(e1);
    } else {
        float4 a = *(const float4*)(as + (size_t)s * 4);
        float4 b = *(const float4*)(ad + (size_t)d * 4);
        float e0 = a.x + b.x, e1 = a.y + b.y, e2 = a.z + b.z, e3 = a.w + b.w;
        e0 = fmaxf(e0, 0.2f * e0);
        e1 = fmaxf(e1, 0.2f * e1);
        e2 = fmaxf(e2, 0.2f * e2);
        e3 = fmaxf(e3, 0.2f * e3);
        wp[i] = __expf(e0);
        wp[(size_t)E + i] = __expf(e1);
        wp[2 * (size_t)E + i] = __expf(e2);
        wp[3 * (size_t)E + i] = __expf(e3);
    }
}

// ---------------- MFMA GEMM + fused alpha epilogue --------------------------
// h[M,256](f16) = A[M,K] @ W[K,256]; Wt = W^T fp16 [256][K]. AF32: A is fp32
// (layer 1 reads x directly). M_rep=2: wave owns 32 rows (two A frags);
// each Bs ds_read_b128 feeds 2 MFMAs. Block = 4 waves = 128 rows. Software
// pipeline: next chunk's stage regs + A frags prefetched during MFMA; raw
// s_barrier with lgkmcnt(0)-only waits (global prefetches stay in flight).
// mfma_f32_16x16x32_f16 layouts (HW-verified): A[m=lane&15][k=quad*8+j];
// B[n=lane&15][k]; D col=lane&15, row=quad*4+reg.
template <int K, int ALOGW, bool AF32>
__global__ __launch_bounds__(256) void k_gemm_mfma(
    const void* __restrict__ Av, const u16* __restrict__ Wt, u16* __restrict__ out,
    float* __restrict__ as_out, float* __restrict__ ad_out,
    const float* __restrict__ alo, const float* __restrict__ ahi,
    const float* __restrict__ dlo, const float* __restrict__ dhi, int M) {
    __shared__ u16 Bs[256 * 40];  // 20KB
    const int tid = threadIdx.x;
    const int wave = tid >> 6;
    const int lane = tid & 63;
    const int li = lane & 15;
    const int quad = lane >> 4;
    const int r0 = blockIdx.x * 128 + wave * 32;
    int ar0 = r0 + li;
    int ar1 = r0 + 16 + li;
    if (ar0 >= M) ar0 = M - 1;  // clamp (stores are guarded)
    if (ar1 >= M) ar1 = M - 1;
    const u16* a16_0 = (const u16*)Av + (size_t)ar0 * K + quad * 8;
    const u16* a16_1 = (const u16*)Av + (size_t)ar1 * K + quad * 8;
    const float* a32_0 = (const float*)Av + (size_t)ar0 * K + quad * 8;
    const float* a32_1 = (const float*)Av + (size_t)ar1 * K + quad * 8;

    f32x4v acc0[16], acc1[16];
#pragma unroll
    for (int ct = 0; ct < 16; ct++) {
        acc0[ct] = (f32x4v)(0.f);
        acc1[ct] = (f32x4v)(0.f);
    }

    const u16* wrow = Wt + (size_t)tid * K;
    u16* dstp = Bs + tid * 40;
    // prologue prefetch (chunk 0)
    uint4 sv0 = ((const uint4*)wrow)[0];
    uint4 sv1 = ((const uint4*)(wrow + 8))[0];
    uint4 sv2 = ((const uint4*)(wrow + 16))[0];
    uint4 sv3 = ((const uint4*)(wrow + 24))[0];
    uint4 p0a, p0b, p1a, p1b;
    if (AF32) {
        p0a = *(const uint4*)(a32_0);
        p0b = *(const uint4*)(a32_0 + 4);
        p1a = *(const uint4*)(a32_1);
        p1b = *(const uint4*)(a32_1 + 4);
    } else {
        p0a = *(const uint4*)(a16_0);
        p1a = *(const uint4*)(a16_1);
        p0b = p0a;
        p1b = p1a;
    }

    for (int t = 0; t < K; t += 32) {
        asm volatile("s_waitcnt lgkmcnt(0)" ::: "memory");
        __builtin_amdgcn_s_barrier();  // Bs free for writing (prior reads done)
        ((uint4*)dstp)[0] = sv0;
        ((uint4*)(dstp + 8))[0] = sv1;
        ((uint4*)(dstp + 16))[0] = sv2;
        ((uint4*)(dstp + 24))[0] = sv3;
        f16x8 a0, a1;
        if (AF32) {
            union { uint4 u; float f[4]; } ua, ub;
            ua.u = p0a; ub.u = p0b;
            a0[0] = (f16)ua.f[0]; a0[1] = (f16)ua.f[1];
            a0[2] = (f16)ua.f[2]; a0[3] = (f16)ua.f[3];
            a0[4] = (f16)ub.f[0]; a0[5] = (f16)ub.f[1];
            a0[6] = (f16)ub.f[2]; a0[7] = (f16)ub.f[3];
            ua.u = p1a; ub.u = p1b;
            a1[0] = (f16)ua.f[0]; a1[1] = (f16)ua.f[1];
            a1[2] = (f16)ua.f[2]; a1[3] = (f16)ua.f[3];
            a1[4] = (f16)ub.f[0]; a1[5] = (f16)ub.f[1];
            a1[6] = (f16)ub.f[2]; a1[7] = (f16)ub.f[3];
        } else {
            union { uint4 u; f16x8 h; } uh;
            uh.u = p0a; a0 = uh.h;
            uh.u = p1a; a1 = uh.h;
        }
        if (t + 32 < K) {  // prefetch next chunk; stays in flight across barrier
            const u16* s2 = wrow + t + 32;
            sv0 = ((const uint4*)s2)[0];
            sv1 = ((const uint4*)(s2 + 8))[0];
            sv2 = ((const uint4*)(s2 + 16))[0];
            sv3 = ((const uint4*)(s2 + 24))[0];
            if (AF32) {
                p0a = *(const uint4*)(a32_0 + t + 32);
                p0b = *(const uint4*)(a32_0 + t + 36);
                p1a = *(const uint4*)(a32_1 + t + 32);
                p1b = *(const uint4*)(a32_1 + t + 36);
            } else {
                p0a = *(const uint4*)(a16_0 + t + 32);
                p1a = *(const uint4*)(a16_1 + t + 32);
            }
        }
        asm volatile("s_waitcnt lgkmcnt(0)" ::: "memory");
        __builtin_amdgcn_s_barrier();  // Bs ready (all ds_writes drained)
#pragma unroll
        for (int ct = 0; ct < 16; ct++) {
            f16x8 b = *(const f16x8*)(Bs + (ct * 16 + li) * 40 + quad * 8);
            acc0[ct] = __builtin_amdgcn_mfma_f32_16x16x32_f16(a0, b, acc0[ct], 0, 0, 0);
            acc1[ct] = __builtin_amdgcn_mfma_f32_16x16x32_f16(a1, b, acc1[ct], 0, 0, 0);
        }
    }

    const int NS = 64 >> ALOGW;   // 2 or 4
    const int SH = ALOGW - 2;     // slot = ct >> SH
    float aw[16], dw[16];
#pragma unroll
    for (int ct = 0; ct < 16; ct++) {
        int col = ct * 16 + li;
        aw[ct] = (col < 128) ? alo[col] : ahi[col - 128];
        dw[ct] = (col < 128) ? dlo[col] : dhi[col - 128];
    }

    auto epilogue = [&](f32x4v(&acc)[16], int rbase) {
        // h store (fp16): D row = quad*4+reg, col = ct*16+li
#pragma unroll
        for (int reg = 0; reg < 4; reg++) {
            int grow = rbase + quad * 4 + reg;
            if (grow < M) {
                u16* orow = out + (size_t)grow * 256 + li;
#pragma unroll
                for (int ct = 0; ct < 16; ct++) orow[ct * 16] = f2h(acc[ct][reg]);
            }
        }
        // fused alpha epilogue
#pragma unroll
        for (int reg = 0; reg < 4; reg++) {
            float s[4] = {0.f, 0.f, 0.f, 0.f};
            float d[4] = {0.f, 0.f, 0.f, 0.f};
#pragma unroll
            for (int ct = 0; ct < 16; ct++) {
                int sl = ct >> SH;
                s[sl] += acc[ct][reg] * aw[ct];
                d[sl] += acc[ct][reg] * dw[ct];
            }
#pragma unroll
            for (int sl = 0; sl < NS; sl++) {
#pragma unroll
                for (int m = 1; m <= 8; m <<= 1) {
                    s[sl] += __shfl_xor(s[sl], m, 64);
                    d[sl] += __shfl_xor(d[sl], m, 64);
                }
            }
            int grow = rbase + quad * 4 + reg;
            if (li == 0 && grow < M) {
#pragma unroll
                for (int sl = 0; sl < NS; sl++) {
                    as_out[(size_t)grow * NS + sl] = s[sl];
                    ad_out[(size_t)grow * NS + sl] = d[sl];
                }
            }
        }
    };
    epilogue(acc0, r0);
    epilogue(acc1, r0 + 16);
}

// ---------------- aggregation (softmax-weighted gather) ----------------------
// Column-half split with XCD-group affinity (R10 form): blockIdx%8 -> XCD;
// xcd<4 -> cols 0-127, xcd>=4 -> cols 128-255. 32-lane half-wave owns one dst
// node per half; lane owns 4 channels (8B gathers). Edge weights PRELOADED
// from wp planes (coalesced by csr position p); 8-wide unroll keeps 8x512B in
// flight per wave. Self-loop weight computed inline from as/ad.
// MODE 0: +bias, ELU, write fp16 x1 [n,256]. MODE 1: +bias, write fp32 mu/ls.
template <int LOGW, int MODE, typename OT>
__global__ __launch_bounds__(256) void k_agg4(
    const u16* __restrict__ h, const int* __restrict__ rowptr,
    const int* __restrict__ csr_src, const float* __restrict__ wp,
    const float* __restrict__ as, const float* __restrict__ ad,
    const float* __restrict__ b_lo, const float* __restrict__ b_hi,
    OT* __restrict__ outp, int n, int nGrp, int E) {
    const int NS = 64 >> LOGW;  // total alpha slots (2 or 4)
    const int bid = blockIdx.x;
    const int xcd = bid & 7;
    const int half = xcd >> 2;                  // 0: cols 0-127, 1: cols 128-255
    const int grp = (bid >> 3) * 4 + (xcd & 3); // node group within half
    if (grp >= nGrp) return;
    const int lane = threadIdx.x & 63;
    const int sub = lane >> 5;   // which node of the wave's pair
    const int sl = lane & 31;    // lane within the node
    const int wid0 = grp * 8 + (threadIdx.x >> 6) * 2 + sub;
    const bool ok = wid0 < n;
    const int wid = ok ? wid0 : (n - 1);  // clamped for safe loads
    const int col = half * 128 + sl * 4;
    const int slot = col >> (LOGW + 2);
    const float* __restrict__ wpl = wp + (size_t)slot * E;

    // self-loop weight
    float e = as[(size_t)wid * NS + slot] + ad[(size_t)wid * NS + slot];
    e = fmaxf(e, 0.2f * e);  // LeakyReLU(0.2)
    float w = __expf(e);
    float denom = w;
    float4 hv = loadh4(h, (size_t)wid * 256 + col);
    float acc0 = w * hv.x, acc1 = w * hv.y, acc2 = w * hv.z, acc3 = w * hv.w;

    int rb = 0, re = 0;
    if (ok) { rb = rowptr[wid0]; re = rowptr[wid0 + 1]; }
    int p = rb;
    for (; p + 8 <= re; p += 8) {
        int4 sA = *(const int4*)(csr_src + p);
        int4 sB = *(const int4*)(csr_src + p + 4);
        float4 wA = *(const float4*)(wpl + p);
        float4 wB = *(const float4*)(wpl + p + 4);
        float4 h0 = loadh4(h, (size_t)sA.x * 256 + col);
        float4 h1 = loadh4(h, (size_t)sA.y * 256 + col);
        float4 h2 = loadh4(h, (size_t)sA.z * 256 + col);
        float4 h3 = loadh4(h, (size_t)sA.w * 256 + col);
        float4 h4 = loadh4(h, (size_t)sB.x * 256 + col);
        float4 h5 = loadh4(h, (size_t)sB.y * 256 + col);
        float4 h6 = loadh4(h, (size_t)sB.z * 256 + col);
        float4 h7 = loadh4(h, (size_t)sB.w * 256 + col);
        denom += (wA.x + wA.y + wA.z + wA.w) + (wB.x + wB.y + wB.z + wB.w);
        acc0 += wA.x * h0.x + wA.y * h1.x + wA.z * h2.x + wA.w * h3.x +
                wB.x * h4.x + wB.y * h5.x + wB.z * h6.x + wB.w * h7.x;
        acc1 += wA.x * h0.y + wA.y * h1.y + wA.z * h2.y + wA.w * h3.y +
                wB.x * h4.y + wB.y * h5.y + wB.z * h6.y + wB.w * h7.y;
        acc2 += wA.x * h0.z + wA.y * h1.z + wA.z * h2.z + wA.w * h3.z +
                wB.x * h4.z + wB.y * h5.z + wB.z * h6.z + wB.w * h7.z;
        acc3 += wA.x * h0.w + wA.y * h1.w + wA.z * h2.w + wA.w * h3.w +
                wB.x * h4.w + wB.y * h5.w + wB.z * h6.w + wB.w * h7.w;
    }
    for (; p + 4 <= re; p += 4) {
        int4 sA = *(const int4*)(csr_src + p);
        float4 wA = *(const float4*)(wpl + p);
        float4 h0 = loadh4(h, (size_t)sA.x * 256 + col);
        float4 h1 = loadh4(h, (size_t)sA.y * 256 + col);
        float4 h2 = loadh4(h, (size_t)sA.z * 256 + col);
        float4 h3 = loadh4(h, (size_t)sA.w * 256 + col);
        denom += (wA.x + wA.y) + (wA.z + wA.w);
        acc0 += wA.x * h0.x + wA.y * h1.x + wA.z * h2.x + wA.w * h3.x;
        acc1 += wA.x * h0.y + wA.y * h1.y + wA.z * h2.y + wA.w * h3.y;
        acc2 += wA.x * h0.z + wA.y * h1.z + wA.z * h2.z + wA.w * h3.z;
        acc3 += wA.x * h0.w + wA.y * h1.w + wA.z * h2.w + wA.w * h3.w;
    }
    for (; p < re; ++p) {
        int s = csr_src[p];
        float ww = wpl[p];
        float4 hh = loadh4(h, (size_t)s * 256 + col);
        denom += ww;
        acc0 += ww * hh.x;
        acc1 += ww * hh.y;
        acc2 += ww * hh.z;
        acc3 += ww * hh.w;
    }
    float inv = 1.0f / (denom + 1e-16f);

    const float* bp = half ? b_hi : b_lo;
    const int ci = sl * 4;
    float4 bv = *(const float4*)(bp + ci);
    float v0 = acc0 * inv + bv.x;
    float v1 = acc1 * inv + bv.y;
    float v2 = acc2 * inv + bv.z;
    float v3 = acc3 * inv + bv.w;

    if (!ok) return;
    if (MODE == 0) {  // ELU -> x1 fp16 [n,256]
        v0 = v0 > 0.f ? v0 : expm1f(v0);
        v1 = v1 > 0.f ? v1 : expm1f(v1);
        v2 = v2 > 0.f ? v2 : expm1f(v2);
        v3 = v3 > 0.f ? v3 : expm1f(v3);
        store4((u16*)outp, (size_t)wid0 * 256 + col, make_float4(v0, v1, v2, v3));
    } else {  // half 0 -> mu [n,128]; half 1 -> logstd [n,128] (concatenated)
        size_t base = half ? ((size_t)n * 128 + (size_t)wid0 * 128 + ci)
                           : ((size_t)wid0 * 128 + ci);
        store4((float*)outp, base, make_float4(v0, v1, v2, v3));
    }
}

// ---------------------------------------------------------------------------
extern "C" void kernel_launch(void* const* d_in, const int* in_sizes, int n_in,
                              void* d_out, int out_size, void* d_ws, size_t ws_size,
                              hipStream_t stream) {
    const float* x = (const float*)d_in[0];
    const u32* ebuf = (const u32*)d_in[1];
    const float* W1 = (const float*)d_in[2];
    const float* a_src1 = (const float*)d_in[3];
    const float* a_dst1 = (const float*)d_in[4];
    const float* b1 = (const float*)d_in[5];
    const float* W_mu = (const float*)d_in[6];
    const float* a_src_mu = (const float*)d_in[7];
    const float* a_dst_mu = (const float*)d_in[8];
    const float* b_mu = (const float*)d_in[9];
    const float* W_ls = (const float*)d_in[10];
    const float* a_src_ls = (const float*)d_in[11];
    const float* a_dst_ls = (const float*)d_in[12];
    const float* b_ls = (const float*)d_in[13];

    const int n = in_sizes[0] / 128;  // 50000
    const int E = in_sizes[1] / 2;    // 800000

    char* base = (char*)d_ws;
    size_t off = 0;
    auto alloc = [&](size_t b) -> char* {
        char* p = base + off;
        off = (off + b + 255) & ~(size_t)255;
        return p;
    };
    int* rowptr = (int*)alloc((size_t)(n + 1) * 4);
    int* cursor = (int*)alloc((size_t)n * 4);
    int* csr = (int*)alloc((size_t)E * 4);
    int* csrd = (int*)alloc((size_t)E * 4);
    int* bsum = (int*)alloc(256 * 4);
    int* eflag = (int*)alloc(256);
    int* se = (int*)alloc((size_t)E * 4);
    int* de = (int*)alloc((size_t)E * 4);
    float* as = (float*)alloc((size_t)n * 4 * 4);
    float* ad = (float*)alloc((size_t)n * 4 * 4);
    float* wp = (float*)alloc((size_t)E * 4 * 4);  // edge-weight planes (<=4)
    u16* W1t = (u16*)alloc(256 * 128 * 2);        // W1^T fp16 [256][128]
    u16* Wt2 = (u16*)alloc(256 * 256 * 2);        // [W_mu|W_ls]^T fp16 [256][256]
    u16* x1h = (u16*)alloc((size_t)n * 256 * 2);  // x1 fp16 [n,256]
    u16* h = (u16*)alloc((size_t)n * 256 * 2);    // h fp16 (both layers)

    const int nb = (n + 255) / 256;
    const int eg = (E + 255) / 256;
    const int gg = (n + 127) / 128;               // 128 rows per GEMM block
    const int nGrp = (n + 7) / 8;                 // 8 dst nodes per block/half
    const int aggGrid = 8 * ((nGrp + 3) / 4);     // 2 halves x 4-XCD groups

    // edge normalize + CSR build (reused by all three convs)
    hipMemsetAsync(cursor, 0, (size_t)n * 4, stream);
    k_detect<<<1, 256, 0, stream>>>(ebuf, eflag);
    k_extract<<<eg, 256, 0, stream>>>(ebuf, E, eflag, se, de, cursor);
    k_scan_a<<<nb, 256, 0, stream>>>(cursor, n, bsum);
    k_scan_b<<<1, 256, 0, stream>>>(bsum, nb);
    k_scan_c<<<nb, 256, 0, stream>>>(cursor, n, bsum, rowptr, cursor, E);
    k_fill<<<eg, 256, 0, stream>>>(se, de, E, cursor, csr, csrd);

    // weight transposes (fp16)
    k_tw<<<(256 * 128 + 255) / 256, 256, 0, stream>>>(W1, W1, 256, 128, W1t);
    k_tw<<<(256 * 256 + 255) / 256, 256, 0, stream>>>(W_mu, W_ls, 128, 256, Wt2);

    // Layer 1: h = x@W1 (MFMA, fp32 A, fused alphas); w planes; aggregate
    k_gemm_mfma<128, 5, true><<<gg, 256, 0, stream>>>(x, W1t, h, as, ad, a_src1,
                                                      a_src1 + 128, a_dst1,
                                                      a_dst1 + 128, n);
    k_w<2><<<eg, 256, 0, stream>>>(csr, csrd, as, ad, wp, E);
    k_agg4<5, 0, u16><<<aggGrid, 256, 0, stream>>>(h, rowptr, csr, wp, as, ad, b1,
                                                   b1 + 128, x1h, n, nGrp, E);

    // Layers mu & ls: h = x1@[W_mu|W_ls] (MFMA, fused alphas); w; aggregate
    k_gemm_mfma<256, 4, false><<<gg, 256, 0, stream>>>(x1h, Wt2, h, as, ad,
                                                       a_src_mu, a_src_ls,
                                                       a_dst_mu, a_dst_ls, n);
    k_w<4><<<eg, 256, 0, stream>>>(csr, csrd, as, ad, wp, E);
    k_agg4<4, 1, float><<<aggGrid, 256, 0, stream>>>(h, rowptr, csr, wp, as, ad,
                                                     b_mu, b_ls, (float*)d_out, n,
                                                     nGrp, E);
}

// Round 6
// 386.248 us; speedup vs baseline: 1.3941x; 1.0056x over previous
//
#include <hip/hip_runtime.h>

// ---------------------------------------------------------------------------
// GAT encoder: x --GATConv(2 heads,128)--> ELU --> {GATConv mu, GATConv ls}
// N=50000, E=800000 (+self loops). fp32 in/out. Edges int32 w/ int64 detect.
// Round 13:
//  * k_agg5: tail elimination. Old loop = ~2x 8-wide iters + 4-wide + ~1.5
//    SERIAL 1-wide tail edges (each a full csr->gather chain ~1000cyc) per
//    node. New: always full 8-wide with per-edge weight masking; csr padded
//    with 8 zeros, wp planes stride E+8, neighbor over-reads weight-masked.
//  * k_detect merged into k_extract (per-block flag recompute, L2 broadcast).
//  * GEMM/M_rep=2, k_w planes, half-split XCD affinity unchanged (R12).
// ---------------------------------------------------------------------------

typedef unsigned short u16;
typedef unsigned int u32;
typedef _Float16 f16;
typedef f16 f16x8 __attribute__((ext_vector_type(8)));
typedef float f32x4v __attribute__((ext_vector_type(4)));

__device__ __forceinline__ u16 f2h(float f) {
    union { f16 h; u16 u; } t;
    t.h = (f16)f;
    return t.u;
}
__device__ __forceinline__ float4 loadh4(const u16* __restrict__ p, size_t i) {
    union { uint2 u; f16 h[4]; } t;
    t.u = *(const uint2*)(p + i);
    return make_float4((float)t.h[0], (float)t.h[1], (float)t.h[2], (float)t.h[3]);
}
__device__ __forceinline__ void store4(float* __restrict__ p, size_t i, float4 v) {
    *(float4*)(p + i) = v;
}
__device__ __forceinline__ void store4(u16* __restrict__ p, size_t i, float4 v) {
    union { uint2 u; f16 h[4]; } t;
    t.h[0] = (f16)v.x; t.h[1] = (f16)v.y; t.h[2] = (f16)v.z; t.h[3] = (f16)v.w;
    *(uint2*)(p + i) = t.u;
}

// ---------------- edge normalize (+int64 detect, +degree count) --------------
__global__ __launch_bounds__(256) void k_extract(const u32* __restrict__ ebuf, int E,
                                                 int* __restrict__ se,
                                                 int* __restrict__ de,
                                                 int* __restrict__ deg) {
    __shared__ int nz;
    if (threadIdx.x == 0) nz = 0;
    __syncthreads();
    if (ebuf[2 * threadIdx.x + 1] != 0u) atomicAdd(&nz, 1);
    __syncthreads();
    const bool i64 = (nz == 0);
    int e = blockIdx.x * 256 + threadIdx.x;
    if (e >= E) return;
    int s, d;
    if (i64) {  // int64 layout
        s = (int)ebuf[2 * (size_t)e];
        d = (int)ebuf[2 * ((size_t)E + (size_t)e)];
    } else {  // int32 layout
        s = (int)ebuf[e];
        d = (int)ebuf[(size_t)E + (size_t)e];
    }
    se[e] = s;
    de[e] = d;
    atomicAdd(&deg[d], 1);
}

// ---------------- CSR build ----------------
__global__ __launch_bounds__(256) void k_scan_a(const int* __restrict__ deg, int n,
                                                int* __restrict__ bsum) {
    __shared__ int s[256];
    int i = blockIdx.x * 256 + threadIdx.x;
    s[threadIdx.x] = (i < n) ? deg[i] : 0;
    __syncthreads();
    for (int st = 128; st > 0; st >>= 1) {
        if (threadIdx.x < st) s[threadIdx.x] += s[threadIdx.x + st];
        __syncthreads();
    }
    if (threadIdx.x == 0) bsum[blockIdx.x] = s[0];
}

__global__ __launch_bounds__(256) void k_scan_b(int* __restrict__ bsum, int nb) {
    __shared__ int s[256];
    int t = threadIdx.x;
    int v = (t < nb) ? bsum[t] : 0;
    s[t] = v;
    __syncthreads();
    for (int off = 1; off < 256; off <<= 1) {
        int add = (t >= off) ? s[t - off] : 0;
        __syncthreads();
        s[t] += add;
        __syncthreads();
    }
    if (t < nb) bsum[t] = s[t] - v;  // exclusive
}

__global__ __launch_bounds__(256) void k_scan_c(const int* __restrict__ deg, int n,
                                                const int* __restrict__ bsum,
                                                int* __restrict__ rowptr,
                                                int* __restrict__ cursor, int E) {
    __shared__ int s[256];
    int t = threadIdx.x;
    int i = blockIdx.x * 256 + t;
    int v = (i < n) ? deg[i] : 0;
    s[t] = v;
    __syncthreads();
    for (int off = 1; off < 256; off <<= 1) {
        int add = (t >= off) ? s[t - off] : 0;
        __syncthreads();
        s[t] += add;
        __syncthreads();
    }
    if (i < n) {
        int ex = bsum[blockIdx.x] + s[t] - v;
        rowptr[i] = ex;
        cursor[i] = ex;
    }
    if (i == 0) rowptr[n] = E;
}

__global__ __launch_bounds__(256) void k_fill(const int* __restrict__ src,
                                              const int* __restrict__ dst, int E,
                                              int* __restrict__ cursor,
                                              int* __restrict__ csr_src,
                                              int* __restrict__ csr_dst) {
    int e = blockIdx.x * 256 + threadIdx.x;
    if (e < 8) csr_src[E + e] = 0;  // pad for masked full-width agg loop
    if (e < E) {
        int d = dst[e];
        int slot = atomicAdd(&cursor[d], 1);
        csr_src[slot] = src[e];
        csr_dst[slot] = d;
    }
}

// Wt[c][k] = W[k][c] as fp16.  split==256: single W (row stride 256);
// split==128: c<128 from Wl, else Wr (row stride 128).
__global__ __launch_bounds__(256) void k_tw(const float* __restrict__ Wl,
                                            const float* __restrict__ Wr, int split,
                                            int K, u16* __restrict__ Wt) {
    int idx = blockIdx.x * 256 + threadIdx.x;
    if (idx >= 256 * K) return;
    int c = idx / K, k = idx - c * K;
    float v;
    if (split == 256)
        v = Wl[(size_t)k * 256 + c];
    else
        v = (c < 128) ? Wl[(size_t)k * 128 + c] : Wr[(size_t)k * 128 + (c - 128)];
    Wt[idx] = f2h(v);
}

// ---------------- edge-weight precompute (CSR order, per-slot planes) --------
// Plane stride Ep = E+8 (pad covered by agg's masking).
template <int NS>
__global__ __launch_bounds__(256) void k_w(const int* __restrict__ csr_src,
                                           const int* __restrict__ csr_dst,
                                           const float* __restrict__ as,
                                           const float* __restrict__ ad,
                                           float* __restrict__ wp, int E, int Ep) {
    int i = blockIdx.x * 256 + threadIdx.x;
    if (i >= E) return;
    int s = csr_src[i], d = csr_dst[i];
    if (NS == 2) {
        float2 a = *(const float2*)(as + (size_t)s * 2);
        float2 b = *(const float2*)(ad + (size_t)d * 2);
        float e0 = a.x + b.x, e1 = a.y + b.y;
        e0 = fmaxf(e0, 0.2f * e0);
        e1 = fmaxf(e1, 0.2f * e1);
        wp[i] = __expf(e0);
        wp[(size_t)Ep + i] = __expf(e1);
    } else {
        float4 a = *(const float4*)(as + (size_t)s * 4);
        float4 b = *(const float4*)(ad + (size_t)d * 4);
        float e0 = a.x + b.x, e1 = a.y + b.y, e2 = a.z + b.z, e3 = a.w + b.w;
        e0 = fmaxf(e0, 0.2f * e0);
        e1 = fmaxf(e1, 0.2f * e1);
        e2 = fmaxf(e2, 0.2f * e2);
        e3 = fmaxf(e3, 0.2f * e3);
        wp[i] = __expf(e0);
        wp[(size_t)Ep + i] = __expf(e1);
        wp[2 * (size_t)Ep + i] = __expf(e2);
        wp[3 * (size_t)Ep + i] = __expf(e3);
    }
}

// ---------------- MFMA GEMM + fused alpha epilogue --------------------------
// h[M,256](f16) = A[M,K] @ W[K,256]; Wt = W^T fp16 [256][K]. AF32: A is fp32
// (layer 1 reads x directly). M_rep=2: wave owns 32 rows (two A frags);
// each Bs ds_read_b128 feeds 2 MFMAs. Block = 4 waves = 128 rows. Software
// pipeline: next chunk's stage regs + A frags prefetched during MFMA; raw
// s_barrier with lgkmcnt(0)-only waits (global prefetches stay in flight).
template <int K, int ALOGW, bool AF32>
__global__ __launch_bounds__(256) void k_gemm_mfma(
    const void* __restrict__ Av, const u16* __restrict__ Wt, u16* __restrict__ out,
    float* __restrict__ as_out, float* __restrict__ ad_out,
    const float* __restrict__ alo, const float* __restrict__ ahi,
    const float* __restrict__ dlo, const float* __restrict__ dhi, int M) {
    __shared__ u16 Bs[256 * 40];  // 20KB
    const int tid = threadIdx.x;
    const int wave = tid >> 6;
    const int lane = tid & 63;
    const int li = lane & 15;
    const int quad = lane >> 4;
    const int r0 = blockIdx.x * 128 + wave * 32;
    int ar0 = r0 + li;
    int ar1 = r0 + 16 + li;
    if (ar0 >= M) ar0 = M - 1;  // clamp (stores are guarded)
    if (ar1 >= M) ar1 = M - 1;
    const u16* a16_0 = (const u16*)Av + (size_t)ar0 * K + quad * 8;
    const u16* a16_1 = (const u16*)Av + (size_t)ar1 * K + quad * 8;
    const float* a32_0 = (const float*)Av + (size_t)ar0 * K + quad * 8;
    const float* a32_1 = (const float*)Av + (size_t)ar1 * K + quad * 8;

    f32x4v acc0[16], acc1[16];
#pragma unroll
    for (int ct = 0; ct < 16; ct++) {
        acc0[ct] = (f32x4v)(0.f);
        acc1[ct] = (f32x4v)(0.f);
    }

    const u16* wrow = Wt + (size_t)tid * K;
    u16* dstp = Bs + tid * 40;
    // prologue prefetch (chunk 0)
    uint4 sv0 = ((const uint4*)wrow)[0];
    uint4 sv1 = ((const uint4*)(wrow + 8))[0];
    uint4 sv2 = ((const uint4*)(wrow + 16))[0];
    uint4 sv3 = ((const uint4*)(wrow + 24))[0];
    uint4 p0a, p0b, p1a, p1b;
    if (AF32) {
        p0a = *(const uint4*)(a32_0);
        p0b = *(const uint4*)(a32_0 + 4);
        p1a = *(const uint4*)(a32_1);
        p1b = *(const uint4*)(a32_1 + 4);
    } else {
        p0a = *(const uint4*)(a16_0);
        p1a = *(const uint4*)(a16_1);
        p0b = p0a;
        p1b = p1a;
    }

    for (int t = 0; t < K; t += 32) {
        asm volatile("s_waitcnt lgkmcnt(0)" ::: "memory");
        __builtin_amdgcn_s_barrier();  // Bs free for writing (prior reads done)
        ((uint4*)dstp)[0] = sv0;
        ((uint4*)(dstp + 8))[0] = sv1;
        ((uint4*)(dstp + 16))[0] = sv2;
        ((uint4*)(dstp + 24))[0] = sv3;
        f16x8 a0, a1;
        if (AF32) {
            union { uint4 u; float f[4]; } ua, ub;
            ua.u = p0a; ub.u = p0b;
            a0[0] = (f16)ua.f[0]; a0[1] = (f16)ua.f[1];
            a0[2] = (f16)ua.f[2]; a0[3] = (f16)ua.f[3];
            a0[4] = (f16)ub.f[0]; a0[5] = (f16)ub.f[1];
            a0[6] = (f16)ub.f[2]; a0[7] = (f16)ub.f[3];
            ua.u = p1a; ub.u = p1b;
            a1[0] = (f16)ua.f[0]; a1[1] = (f16)ua.f[1];
            a1[2] = (f16)ua.f[2]; a1[3] = (f16)ua.f[3];
            a1[4] = (f16)ub.f[0]; a1[5] = (f16)ub.f[1];
            a1[6] = (f16)ub.f[2]; a1[7] = (f16)ub.f[3];
        } else {
            union { uint4 u; f16x8 h; } uh;
            uh.u = p0a; a0 = uh.h;
            uh.u = p1a; a1 = uh.h;
        }
        if (t + 32 < K) {  // prefetch next chunk; stays in flight across barrier
            const u16* s2 = wrow + t + 32;
            sv0 = ((const uint4*)s2)[0];
            sv1 = ((const uint4*)(s2 + 8))[0];
            sv2 = ((const uint4*)(s2 + 16))[0];
            sv3 = ((const uint4*)(s2 + 24))[0];
            if (AF32) {
                p0a = *(const uint4*)(a32_0 + t + 32);
                p0b = *(const uint4*)(a32_0 + t + 36);
                p1a = *(const uint4*)(a32_1 + t + 32);
                p1b = *(const uint4*)(a32_1 + t + 36);
            } else {
                p0a = *(const uint4*)(a16_0 + t + 32);
                p1a = *(const uint4*)(a16_1 + t + 32);
            }
        }
        asm volatile("s_waitcnt lgkmcnt(0)" ::: "memory");
        __builtin_amdgcn_s_barrier();  // Bs ready (all ds_writes drained)
#pragma unroll
        for (int ct = 0; ct < 16; ct++) {
            f16x8 b = *(const f16x8*)(Bs + (ct * 16 + li) * 40 + quad * 8);
            acc0[ct] = __builtin_amdgcn_mfma_f32_16x16x32_f16(a0, b, acc0[ct], 0, 0, 0);
            acc1[ct] = __builtin_amdgcn_mfma_f32_16x16x32_f16(a1, b, acc1[ct], 0, 0, 0);
        }
    }

    const int NS = 64 >> ALOGW;   // 2 or 4
    const int SH = ALOGW - 2;     // slot = ct >> SH
    float aw[16], dw[16];
#pragma unroll
    for (int ct = 0; ct < 16; ct++) {
        int col = ct * 16 + li;
        aw[ct] = (col < 128) ? alo[col] : ahi[col - 128];
        dw[ct] = (col < 128) ? dlo[col] : dhi[col - 128];
    }

    auto epilogue = [&](f32x4v(&acc)[16], int rbase) {
        // h store (fp16): D row = quad*4+reg, col = ct*16+li
#pragma unroll
        for (int reg = 0; reg < 4; reg++) {
            int grow = rbase + quad * 4 + reg;
            if (grow < M) {
                u16* orow = out + (size_t)grow * 256 + li;
#pragma unroll
                for (int ct = 0; ct < 16; ct++) orow[ct * 16] = f2h(acc[ct][reg]);
            }
        }
        // fused alpha epilogue
#pragma unroll
        for (int reg = 0; reg < 4; reg++) {
            float s[4] = {0.f, 0.f, 0.f, 0.f};
            float d[4] = {0.f, 0.f, 0.f, 0.f};
#pragma unroll
            for (int ct = 0; ct < 16; ct++) {
                int sl = ct >> SH;
                s[sl] += acc[ct][reg] * aw[ct];
                d[sl] += acc[ct][reg] * dw[ct];
            }
#pragma unroll
            for (int sl = 0; sl < NS; sl++) {
#pragma unroll
                for (int m = 1; m <= 8; m <<= 1) {
                    s[sl] += __shfl_xor(s[sl], m, 64);
                    d[sl] += __shfl_xor(d[sl], m, 64);
                }
            }
            int grow = rbase + quad * 4 + reg;
            if (li == 0 && grow < M) {
#pragma unroll
                for (int sl = 0; sl < NS; sl++) {
                    as_out[(size_t)grow * NS + sl] = s[sl];
                    ad_out[(size_t)grow * NS + sl] = d[sl];
                }
            }
        }
    };
    epilogue(acc0, r0);
    epilogue(acc1, r0 + 16);
}

// ---------------- aggregation (softmax-weighted gather) ----------------------
// Column-half split with XCD-group affinity; 32-lane half-wave owns one dst
// node per half; lane owns 4 channels (8B gathers). Weights from wp planes.
// FULL-WIDTH 8-wide loop, no tails: past-degree lanes weight-masked to 0;
// csr over-reads hit neighbor entries (valid ids) or the zero pad.
// MODE 0: +bias, ELU, write fp16 x1 [n,256]. MODE 1: +bias, write fp32 mu/ls.
template <int LOGW, int MODE, typename OT>
__global__ __launch_bounds__(256) void k_agg5(
    const u16* __restrict__ h, const int* __restrict__ rowptr,
    const int* __restrict__ csr_src, const float* __restrict__ wp,
    const float* __restrict__ as, const float* __restrict__ ad,
    const float* __restrict__ b_lo, const float* __restrict__ b_hi,
    OT* __restrict__ outp, int n, int nGrp, int Ep) {
    const int NS = 64 >> LOGW;  // total alpha slots (2 or 4)
    const int bid = blockIdx.x;
    const int xcd = bid & 7;
    const int half = xcd >> 2;                  // 0: cols 0-127, 1: cols 128-255
    const int grp = (bid >> 3) * 4 + (xcd & 3); // node group within half
    if (grp >= nGrp) return;
    const int lane = threadIdx.x & 63;
    const int sub = lane >> 5;   // which node of the wave's pair
    const int sl = lane & 31;    // lane within the node
    const int wid0 = grp * 8 + (threadIdx.x >> 6) * 2 + sub;
    const bool ok = wid0 < n;
    const int wid = ok ? wid0 : (n - 1);  // clamped for safe loads
    const int col = half * 128 + sl * 4;
    const int slot = col >> (LOGW + 2);
    const float* __restrict__ wpl = wp + (size_t)slot * Ep;

    // self-loop weight
    float e = as[(size_t)wid * NS + slot] + ad[(size_t)wid * NS + slot];
    e = fmaxf(e, 0.2f * e);  // LeakyReLU(0.2)
    float w = __expf(e);
    float denom = w;
    float4 hv = loadh4(h, (size_t)wid * 256 + col);
    float acc0 = w * hv.x, acc1 = w * hv.y, acc2 = w * hv.z, acc3 = w * hv.w;

    int rb = 0, re = 0;
    if (ok) { rb = rowptr[wid0]; re = rowptr[wid0 + 1]; }
    for (int p = rb; p < re; p += 8) {
        int4 sA = *(const int4*)(csr_src + p);
        int4 sB = *(const int4*)(csr_src + p + 4);
        float4 wA = *(const float4*)(wpl + p);
        float4 wB = *(const float4*)(wpl + p + 4);
        int rem = re - p;  // >= 1
        float w0 = wA.x;
        float w1 = (rem > 1) ? wA.y : 0.f;
        float w2 = (rem > 2) ? wA.z : 0.f;
        float w3 = (rem > 3) ? wA.w : 0.f;
        float w4 = (rem > 4) ? wB.x : 0.f;
        float w5 = (rem > 5) ? wB.y : 0.f;
        float w6 = (rem > 6) ? wB.z : 0.f;
        float w7 = (rem > 7) ? wB.w : 0.f;
        float4 h0 = loadh4(h, (size_t)sA.x * 256 + col);
        float4 h1 = loadh4(h, (size_t)sA.y * 256 + col);
        float4 h2 = loadh4(h, (size_t)sA.z * 256 + col);
        float4 h3 = loadh4(h, (size_t)sA.w * 256 + col);
        float4 h4 = loadh4(h, (size_t)sB.x * 256 + col);
        float4 h5 = loadh4(h, (size_t)sB.y * 256 + col);
        float4 h6 = loadh4(h, (size_t)sB.z * 256 + col);
        float4 h7 = loadh4(h, (size_t)sB.w * 256 + col);
        denom += (w0 + w1 + w2 + w3) + (w4 + w5 + w6 + w7);
        acc0 += w0 * h0.x + w1 * h1.x + w2 * h2.x + w3 * h3.x +
                w4 * h4.x + w5 * h5.x + w6 * h6.x + w7 * h7.x;
        acc1 += w0 * h0.y + w1 * h1.y + w2 * h2.y + w3 * h3.y +
                w4 * h4.y + w5 * h5.y + w6 * h6.y + w7 * h7.y;
        acc2 += w0 * h0.z + w1 * h1.z + w2 * h2.z + w3 * h3.z +
                w4 * h4.z + w5 * h5.z + w6 * h6.z + w7 * h7.z;
        acc3 += w0 * h0.w + w1 * h1.w + w2 * h2.w + w3 * h3.w +
                w4 * h4.w + w5 * h5.w + w6 * h6.w + w7 * h7.w;
    }
    float inv = 1.0f / (denom + 1e-16f);

    const float* bp = half ? b_hi : b_lo;
    const int ci = sl * 4;
    float4 bv = *(const float4*)(bp + ci);
    float v0 = acc0 * inv + bv.x;
    float v1 = acc1 * inv + bv.y;
    float v2 = acc2 * inv + bv.z;
    float v3 = acc3 * inv + bv.w;

    if (!ok) return;
    if (MODE == 0) {  // ELU -> x1 fp16 [n,256]
        v0 = v0 > 0.f ? v0 : expm1f(v0);
        v1 = v1 > 0.f ? v1 : expm1f(v1);
        v2 = v2 > 0.f ? v2 : expm1f(v2);
        v3 = v3 > 0.f ? v3 : expm1f(v3);
        store4((u16*)outp, (size_t)wid0 * 256 + col, make_float4(v0, v1, v2, v3));
    } else {  // half 0 -> mu [n,128]; half 1 -> logstd [n,128] (concatenated)
        size_t base = half ? ((size_t)n * 128 + (size_t)wid0 * 128 + ci)
                           : ((size_t)wid0 * 128 + ci);
        store4((float*)outp, base, make_float4(v0, v1, v2, v3));
    }
}

// ---------------------------------------------------------------------------
extern "C" void kernel_launch(void* const* d_in, const int* in_sizes, int n_in,
                              void* d_out, int out_size, void* d_ws, size_t ws_size,
                              hipStream_t stream) {
    const float* x = (const float*)d_in[0];
    const u32* ebuf = (const u32*)d_in[1];
    const float* W1 = (const float*)d_in[2];
    const float* a_src1 = (const float*)d_in[3];
    const float* a_dst1 = (const float*)d_in[4];
    const float* b1 = (const float*)d_in[5];
    const float* W_mu = (const float*)d_in[6];
    const float* a_src_mu = (const float*)d_in[7];
    const float* a_dst_mu = (const float*)d_in[8];
    const float* b_mu = (const float*)d_in[9];
    const float* W_ls = (const float*)d_in[10];
    const float* a_src_ls = (const float*)d_in[11];
    const float* a_dst_ls = (const float*)d_in[12];
    const float* b_ls = (const float*)d_in[13];

    const int n = in_sizes[0] / 128;  // 50000
    const int E = in_sizes[1] / 2;    // 800000
    const int Ep = E + 8;             // padded csr/wp stride

    char* base = (char*)d_ws;
    size_t off = 0;
    auto alloc = [&](size_t b) -> char* {
        char* p = base + off;
        off = (off + b + 255) & ~(size_t)255;
        return p;
    };
    int* rowptr = (int*)alloc((size_t)(n + 1) * 4);
    int* cursor = (int*)alloc((size_t)n * 4);
    int* csr = (int*)alloc((size_t)Ep * 4);
    int* csrd = (int*)alloc((size_t)E * 4);
    int* bsum = (int*)alloc(256 * 4);
    int* se = (int*)alloc((size_t)E * 4);
    int* de = (int*)alloc((size_t)E * 4);
    float* as = (float*)alloc((size_t)n * 4 * 4);
    float* ad = (float*)alloc((size_t)n * 4 * 4);
    float* wp = (float*)alloc((size_t)Ep * 4 * 4);  // edge-weight planes (<=4)
    u16* W1t = (u16*)alloc(256 * 128 * 2);        // W1^T fp16 [256][128]
    u16* Wt2 = (u16*)alloc(256 * 256 * 2);        // [W_mu|W_ls]^T fp16 [256][256]
    u16* x1h = (u16*)alloc((size_t)n * 256 * 2);  // x1 fp16 [n,256]
    u16* h = (u16*)alloc((size_t)n * 256 * 2);    // h fp16 (both layers)

    const int nb = (n + 255) / 256;
    const int eg = (E + 255) / 256;
    const int gg = (n + 127) / 128;               // 128 rows per GEMM block
    const int nGrp = (n + 7) / 8;                 // 8 dst nodes per block/half
    const int aggGrid = 8 * ((nGrp + 3) / 4);     // 2 halves x 4-XCD groups

    // edge normalize + CSR build (reused by all three convs)
    hipMemsetAsync(cursor, 0, (size_t)n * 4, stream);
    k_extract<<<eg, 256, 0, stream>>>(ebuf, E, se, de, cursor);
    k_scan_a<<<nb, 256, 0, stream>>>(cursor, n, bsum);
    k_scan_b<<<1, 256, 0, stream>>>(bsum, nb);
    k_scan_c<<<nb, 256, 0, stream>>>(cursor, n, bsum, rowptr, cursor, E);
    k_fill<<<eg, 256, 0, stream>>>(se, de, E, cursor, csr, csrd);

    // weight transposes (fp16)
    k_tw<<<(256 * 128 + 255) / 256, 256, 0, stream>>>(W1, W1, 256, 128, W1t);
    k_tw<<<(256 * 256 + 255) / 256, 256, 0, stream>>>(W_mu, W_ls, 128, 256, Wt2);

    // Layer 1: h = x@W1 (MFMA, fp32 A, fused alphas); w planes; aggregate
    k_gemm_mfma<128, 5, true><<<gg, 256, 0, stream>>>(x, W1t, h, as, ad, a_src1,
                                                      a_src1 + 128, a_dst1,
                                                      a_dst1 + 128, n);
    k_w<2><<<eg, 256, 0, stream>>>(csr, csrd, as, ad, wp, E, Ep);
    k_agg5<5, 0, u16><<<aggGrid, 256, 0, stream>>>(h, rowptr, csr, wp, as, ad, b1,
                                                   b1 + 128, x1h, n, nGrp, Ep);

    // Layers mu & ls: h = x1@[W_mu|W_ls] (MFMA, fused alphas); w; aggregate
    k_gemm_mfma<256, 4, false><<<gg, 256, 0, stream>>>(x1h, Wt2, h, as, ad,
                                                       a_src_mu, a_src_ls,
                                                       a_dst_mu, a_dst_ls, n);
    k_w<4><<<eg, 256, 0, stream>>>(csr, csrd, as, ad, wp, E, Ep);
    k_agg5<4, 1, float><<<aggGrid, 256, 0, stream>>>(h, rowptr, csr, wp, as, ad,
                                                     b_mu, b_ls, (float*)d_out, n,
                                                     nGrp, Ep);
}